// Round 22
// baseline (202.292 us; speedup 1.0000x reference)
//
#include <hip/hip_runtime.h>
#include <hip/hip_fp16.h>

#define H 128
#define ND 4096
#define MAXG 128  // gl2 slots per drug (observed max ~77; 128 = 11 sigma)

// K1: zero gcnt; psexp[p] = exp(ph[p].w_attn); QUARTER-SLICED fp16 table
// phq[4][NP][32] (each slice 3.2MB -> fits one XCD L2); boundary MARKS
// (pure neighbor-compare streaming). gs/ge NOT pre-zeroed: k_p2 validates
// marks against gid directly (poison-proof, replay-proof).
__global__ void k1(const float* __restrict__ ph,
                   const float* __restrict__ w_attn,
                   const int* __restrict__ gid,
                   float* __restrict__ psexp,
                   __half* __restrict__ phq,
                   int* __restrict__ gcnt,
                   int* __restrict__ gs, int* __restrict__ ge,
                   int NP, int E) {
    int gt = blockIdx.x * blockDim.x + threadIdx.x;
    int nthr = gridDim.x * blockDim.x;
    for (int i = gt; i < ND; i += nthr) gcnt[i] = 0;
    for (int t = gt; t < E; t += nthr) {
        int g = gid[t];
        int gp = (t > 0) ? gid[t - 1] : -1;
        int gn = (t + 1 < E) ? gid[t + 1] : -1;
        if (gp != g) gs[g] = t + 1;     // start+1
        if (gn != g) ge[g] = t + 1;     // end
    }
    int lane = threadIdx.x & 63;
    int half_ = lane >> 5;
    int l32  = lane & 31;
    int nw   = nthr >> 6;
    float4 wa = *(const float4*)(w_attn + 4 * l32);
    for (int r0 = (gt >> 6) * 2; r0 < NP; r0 += nw * 2) {
        int row = r0 + half_;           // NP even -> row < NP
        float4 v = *(const float4*)(ph + (size_t)row * H + 4 * l32);
        ushort4 pk;
        pk.x = __half_as_ushort(__float2half(v.x));
        pk.y = __half_as_ushort(__float2half(v.y));
        pk.z = __half_as_ushort(__float2half(v.z));
        pk.w = __half_as_ushort(__float2half(v.w));
        int qq = l32 >> 3;              // quarter = dims [32q, 32q+32)
        *(ushort4*)(phq + ((size_t)qq * NP + row) * 32 + (l32 & 7) * 4) = pk;
        float d = v.x * wa.x + v.y * wa.y + v.z * wa.z + v.w * wa.w;
        #pragma unroll
        for (int off = 16; off >= 1; off >>= 1) d += __shfl_xor(d, off, 64);
        if (l32 == 0) psexp[row] = __expf(d);  // raw exp: scores ~N(0,1), f32-safe
    }
}

// K_p2: t<E: pw[t] = prot_idx | fp16(exp-weight)<<16 (coalesced stream).
//       t<G: validate marks against gid (rejects poison; stale replay values
//       are identical hence valid; empty groups can never validate) and
//       append {start,len} to the owning drug's list.
__global__ void k_p2(const int* __restrict__ gid,
                     const int* __restrict__ prot_idx,
                     const float* __restrict__ psexp,
                     const int* __restrict__ gs, const int* __restrict__ ge,
                     const int* __restrict__ g2d,
                     int* __restrict__ gcnt, int2* __restrict__ gl2,
                     unsigned* __restrict__ pw, int E, int G) {
    int t = blockIdx.x * blockDim.x + threadIdx.x;
    if (t < E) {
        int p = prot_idx[t];
        unsigned short hb = __half_as_ushort(__float2half(psexp[p]));
        pw[t] = (unsigned)p | ((unsigned)hb << 16);
    }
    if (t < G) {
        int s = gs[t], e = ge[t];
        bool ok = (s >= 1) && (s <= E) && (e >= s) && (e <= E);
        if (ok) ok = (gid[s - 1] == t) && (s == 1 || gid[s - 2] != t) &&
                     (gid[e - 1] == t) && (e == E || gid[e] != t);
        if (ok) {
            int d = g2d[t];
            int slot = atomicAdd(&gcnt[d], 1);
            if (slot < MAXG) gl2[d * MAXG + slot] = make_int2(s - 1, e - s + 1);
        }
    }
}

// K_fused_drug: one block per (drug, quarter); quarter q pinned to XCD pair
// {2q,2q+1} via bid&7 (r20: FETCH 205->102 MB, slices go L2-resident).
// lane = (slot=lane>>2 -> entry 0..15, sub=lane&3 -> dims [8*sub,8*sub+8)
// of the quarter). ONE uint4 gather = 16 complete 64B row-quarters with
// ZERO lane duplication (64 lanes x 16B = 16 x 64B). fp16 __hfma2
// accumulation (4 pk-fma vs r20's 16 unpack+fmac: the fix for r20's 66%
// VALUBusy). Per-group pw FIRST-WORD PREFETCH (groups avg 10 entries = 1
// iter, so this takes the stream load off the critical chain). 4 waves =
// 4 group-chunks; denom via shfl_xor masks 4..32; in-block LDS reduce;
// block is SOLE writer of its (d,q) 32-dim span -> plain stores, no
// atomics, no dsum zeroing, no fences.
__global__ void k_fused_drug(const __half* __restrict__ phq,
                             const unsigned* __restrict__ pw,
                             const int2* __restrict__ gl2,
                             const int* __restrict__ gcnt,
                             float* __restrict__ dsum, int NP) {
    __shared__ float xbuf[4][32];
    int bid  = blockIdx.x;
    int s8   = bid & 7;
    int q    = s8 >> 1;
    int d    = ((bid >> 3) << 1) | (s8 & 1);
    int w    = threadIdx.x >> 6;       // wave = group chunk 0..3
    int lane = threadIdx.x & 63;
    int slot = lane >> 2;              // entry slot 0..15
    int sub  = lane & 3;               // dim-octet within quarter
    int gn = gcnt[d];
    if (gn > MAXG) gn = MAXG;
    const int2* gl = gl2 + d * MAXG;
    const __half* base = phq + (size_t)q * NP * 32 + sub * 8;
    float ax[8];
    #pragma unroll
    for (int k = 0; k < 8; ++k) ax[k] = 0.f;
    int2 A = (w < gn) ? gl[w] : make_int2(0, 0);
    unsigned uvp = 0;
    if (w < gn) uvp = pw[A.x + min(slot, A.y - 1)];     // prefetch first word
    for (int i = w; i < gn; i += 4) {
        int2 An = make_int2(0, 0);
        unsigned uvpn = 0;
        if (i + 4 < gn) {
            An = gl[i + 4];
            uvpn = pw[An.x + min(slot, An.y - 1)];      // prefetch next group
        }
        int s0  = __builtin_amdgcn_readfirstlane(A.x);
        int len = __builtin_amdgcn_readfirstlane(A.y);
        float sa = 0.f;
        __half2 hgx[4];
        #pragma unroll
        for (int k = 0; k < 4; ++k) hgx[k] = __float2half2_rn(0.f);
        for (int e = 0; e < len; e += 16) {
            int ii = e + slot;
            int ic = min(ii, len - 1);
            unsigned uv = (e == 0) ? uvp : pw[s0 + ic];
            bool valid = ii < len;
            unsigned short hb = valid ? (unsigned short)(uv >> 16)
                                      : (unsigned short)0;
            __half hw = __ushort_as_half(hb);
            int p = (int)(uv & 0xffffu);
            uint4 r = *(const uint4*)(base + (size_t)p * 32);  // 16 rows/instr
            __half2 hw2 = __half2half2(hw);
            sa += __half2float(hw);
            const __half2* rh = (const __half2*)&r;
            hgx[0] = __hfma2(hw2, rh[0], hgx[0]);
            hgx[1] = __hfma2(hw2, rh[1], hgx[1]);
            hgx[2] = __hfma2(hw2, rh[2], hgx[2]);
            hgx[3] = __hfma2(hw2, rh[3], hgx[3]);
        }
        // denom: sum the 16 slots (4 dup lanes per slot agree): masks 4..32
        float st = sa;
        st += __shfl_xor(st, 4, 64);
        st += __shfl_xor(st, 8, 64);
        st += __shfl_xor(st, 16, 64);
        st += __shfl_xor(st, 32, 64);
        float inv = 1.0f / st;
        ax[0] += __low2float(hgx[0])  * inv;
        ax[1] += __high2float(hgx[0]) * inv;
        ax[2] += __low2float(hgx[1])  * inv;
        ax[3] += __high2float(hgx[1]) * inv;
        ax[4] += __low2float(hgx[2])  * inv;
        ax[5] += __high2float(hgx[2]) * inv;
        ax[6] += __low2float(hgx[3])  * inv;
        ax[7] += __high2float(hgx[3]) * inv;
        A = An;
        uvp = uvpn;
    }
    // reduce across the 16 slots
    #pragma unroll
    for (int k = 0; k < 8; ++k) {
        ax[k] += __shfl_xor(ax[k], 4, 64);
        ax[k] += __shfl_xor(ax[k], 8, 64);
        ax[k] += __shfl_xor(ax[k], 16, 64);
        ax[k] += __shfl_xor(ax[k], 32, 64);
    }
    if (slot == 0) {                   // lanes 0..3 hold the quarter's sums
        *(float4*)&xbuf[w][8 * sub]     = make_float4(ax[0], ax[1], ax[2], ax[3]);
        *(float4*)&xbuf[w][8 * sub + 4] = make_float4(ax[4], ax[5], ax[6], ax[7]);
    }
    __syncthreads();
    if (threadIdx.x < 32) {
        int t = threadIdx.x;
        float v = xbuf[0][t] + xbuf[1][t] + xbuf[2][t] + xbuf[3][t];
        dsum[(size_t)d * H + q * 32 + t] = v;   // sole writer: plain store
    }
}

// K4: one block (128 threads) per drug. fingerprint staged in LDS, each
// thread j dots its own w_out row (float4, L2-resident) + bias + ReLU.
__global__ void k4_out(const float* __restrict__ dsum,
                       const int* __restrict__ gcnt,
                       const float* __restrict__ w_out,
                       const float* __restrict__ b_out,
                       float* __restrict__ out) {
    __shared__ float fp[H];
    int d = blockIdx.x;
    int j = threadIdx.x;
    int c = gcnt[d];
    float f = 0.f;
    if (c > 0) f = dsum[(size_t)d * H + j] / (float)c;
    fp[j] = f;
    __syncthreads();
    const float4* wrow = (const float4*)(w_out + (size_t)j * H);
    const float4* fvec = (const float4*)fp;
    float acc = 0.f;
    #pragma unroll
    for (int i = 0; i < H / 4; ++i) {
        float4 w4 = wrow[i];
        float4 f4 = fvec[i];
        acc += w4.x * f4.x + w4.y * f4.y + w4.z * f4.z + w4.w * f4.w;
    }
    acc += b_out[j];
    out[(size_t)d * H + j] = fmaxf(acc, 0.f);
}

extern "C" void kernel_launch(void* const* d_in, const int* in_sizes, int n_in,
                              void* d_out, int out_size, void* d_ws, size_t ws_size,
                              hipStream_t stream) {
    const float* protein_h = (const float*)d_in[0];
    const float* w_attn    = (const float*)d_in[1];
    const float* w_out     = (const float*)d_in[2];
    const float* b_out     = (const float*)d_in[3];
    const int*   prot_idx  = (const int*)d_in[4];
    const int*   group_ids = (const int*)d_in[5];
    const int*   g2d       = (const int*)d_in[6];

    const int E  = in_sizes[4];
    const int G  = in_sizes[6];
    const int NP = in_sizes[0] / H;

    // Workspace (~29 MB): phq | psexp | pw(+16) | gs | ge | gl2 | gcnt | dsum
    __half*   phq   = (__half*)d_ws;                      // 4*NP*32 fp16
    float*    psexp = (float*)(phq + (size_t)NP * H);     // NP
    unsigned* pw    = (unsigned*)(psexp + NP);            // E + 16
    int*      gs    = (int*)(pw + E + 16);                // G (validated, not zeroed)
    int*      ge    = gs + G;                             // G
    int2*     gl2   = (int2*)(ge + G);                    // ND*MAXG
    int*      gcnt  = (int*)(gl2 + (size_t)ND * MAXG);    // ND (zeroed in k1)
    float*    dsum  = (float*)(gcnt + ND);                // ND*H (fully overwritten)

    // Node 1: zero gcnt + psexp + quarter-sliced fp16 table + marks.
    k1<<<4096, 256, 0, stream>>>(protein_h, w_attn, group_ids, psexp, phq,
                                 gcnt, gs, ge, NP, E);

    // Node 2: pw stream + validated group-list build.
    k_p2<<<(E + 255) / 256, 256, 0, stream>>>(group_ids, prot_idx, psexp,
                                              gs, ge, g2d, gcnt, gl2, pw, E, G);

    // Node 3: (drug x quarter) fp16 pooling, XCD-pinned slices, plain stores.
    k_fused_drug<<<ND * 4, 256, 0, stream>>>(phq, pw, gl2, gcnt, dsum, NP);

    // Node 4: fingerprint + out_proj + ReLU.
    k4_out<<<ND, H, 0, stream>>>(dsum, gcnt, w_out, b_out, (float*)d_out);
}

// Round 23
// 123.811 us; speedup vs baseline: 1.6339x; 1.6339x over previous
//
#include <hip/hip_runtime.h>
#include <hip/hip_fp16.h>

#define H 128
#define ND 4096
#define CH 8      // waves (group-chunks) per drug
#define MAXG 128  // gl2 slots per drug (observed max ~77; 128 = 11 sigma)
#define ZDW (ND + ND * H)   // dwords to zero: gcnt | dsum
#define DPB 8     // drugs per k4 block

// Select component `slot` (0..3) of a uniform uint4 -- 3 v_cndmask.
__device__ __forceinline__ unsigned sel4(uint4 q, int slot) {
    unsigned a = (slot & 1) ? q.y : q.x;
    unsigned b = (slot & 1) ? q.w : q.z;
    return (slot & 2) ? b : a;
}

// K1: zero gcnt|dsum; psexp[p] = exp(ph[p].w_attn) + phh[p] = FP16(ph[p]);
// boundary MARKS (pure neighbor-compare streaming). gs/ge NOT pre-zeroed:
// k_p2 validates marks against gid directly (poison-proof, replay-proof).
__global__ void k1(const float* __restrict__ ph,
                   const float* __restrict__ w_attn,
                   const int* __restrict__ gid,
                   float* __restrict__ psexp,
                   __half* __restrict__ phh,
                   int* __restrict__ zbase,
                   int* __restrict__ gs, int* __restrict__ ge,
                   int NP, int E) {
    int gt = blockIdx.x * blockDim.x + threadIdx.x;
    int nthr = gridDim.x * blockDim.x;
    for (int i = gt; i < ZDW; i += nthr) zbase[i] = 0;
    for (int t = gt; t < E; t += nthr) {
        int g = gid[t];
        int gp = (t > 0) ? gid[t - 1] : -1;
        int gn = (t + 1 < E) ? gid[t + 1] : -1;
        if (gp != g) gs[g] = t + 1;     // start+1
        if (gn != g) ge[g] = t + 1;     // end
    }
    int lane = threadIdx.x & 63;
    int half_ = lane >> 5;
    int l32  = lane & 31;
    int nw   = nthr >> 6;
    float4 wa = *(const float4*)(w_attn + 4 * l32);
    for (int r0 = (gt >> 6) * 2; r0 < NP; r0 += nw * 2) {
        int row = r0 + half_;           // NP even -> row < NP
        float4 v = *(const float4*)(ph + (size_t)row * H + 4 * l32);
        ushort4 pk;
        pk.x = __half_as_ushort(__float2half(v.x));
        pk.y = __half_as_ushort(__float2half(v.y));
        pk.z = __half_as_ushort(__float2half(v.z));
        pk.w = __half_as_ushort(__float2half(v.w));
        *(ushort4*)(phh + (size_t)row * H + 4 * l32) = pk;
        float d = v.x * wa.x + v.y * wa.y + v.z * wa.z + v.w * wa.w;
        #pragma unroll
        for (int off = 16; off >= 1; off >>= 1) d += __shfl_xor(d, off, 64);
        if (l32 == 0) psexp[row] = __expf(d);  // raw exp: scores ~N(0,1), f32-safe
    }
}

// K_p2: t<E: pw[t] = prot_idx | fp16(exp-weight)<<16 (coalesced stream).
//       t<G: validate marks against gid (rejects poison; stale replay values
//       are identical hence valid; empty groups can never validate) and
//       append {start,len} to the owning drug's list.
__global__ void k_p2(const int* __restrict__ gid,
                     const int* __restrict__ prot_idx,
                     const float* __restrict__ psexp,
                     const int* __restrict__ gs, const int* __restrict__ ge,
                     const int* __restrict__ g2d,
                     int* __restrict__ gcnt, int2* __restrict__ gl2,
                     unsigned* __restrict__ pw, int E, int G) {
    int t = blockIdx.x * blockDim.x + threadIdx.x;
    if (t < E) {
        int p = prot_idx[t];
        unsigned short hb = __half_as_ushort(__float2half(psexp[p]));
        pw[t] = (unsigned)p | ((unsigned)hb << 16);
    }
    if (t < G) {
        int s = gs[t], e = ge[t];
        bool ok = (s >= 1) && (s <= E) && (e >= s) && (e <= E);
        if (ok) ok = (gid[s - 1] == t) && (s == 1 || gid[s - 2] != t) &&
                     (gid[e - 1] == t) && (e == E || gid[e] != t);
        if (ok) {
            int d = g2d[t];
            int slot = atomicAdd(&gcnt[d], 1);
            if (slot < MAXG) gl2[d * MAXG + slot] = make_int2(s - 1, e - s + 1);
        }
    }
}

// K_fused_drug: r21 structure + NEXT-GROUP pw-quad software pipeline: the
// next group's descriptor AND its first 16 pw words are s_loaded at the top
// of the current group's iteration, so the ~200cyc L2 s_load is off the
// next group's critical chain (avg group = 10 entries = exactly 1 batch).
// lane = (slot=lane>>4, sub=lane&15); 3-cndmask lane distribution; uint4
// gather = 4 complete 256B fp16 rows/instr; fp16 __hfma2 accumulation;
// shfl_xor denom; per-wave LDS transpose flush; 2 full-wave atomics.
__global__ void k_fused_drug(const __half* __restrict__ phh,
                             const unsigned* __restrict__ pw,
                             const int2* __restrict__ gl2,
                             const int* __restrict__ gcnt,
                             float* __restrict__ dsum) {
    __shared__ float xbuf[4][H];
    int w    = threadIdx.x >> 6;
    int lane = threadIdx.x & 63;
    int slot = lane >> 4;
    int sub  = lane & 15;
    int wid  = (blockIdx.x * blockDim.x + threadIdx.x) >> 6;
    wid = __builtin_amdgcn_readfirstlane(wid);   // wave-uniform -> SGPR
    int d = wid >> 3;          // wid / CH
    int c = wid & (CH - 1);
    if (d >= ND) return;
    int gn = gcnt[d];
    if (gn > MAXG) gn = MAXG;
    const int2* gl = gl2 + d * MAXG;
    const __half* base = phh + sub * 8;
    float ax[8];
    #pragma unroll
    for (int k = 0; k < 8; ++k) ax[k] = 0.f;
    int2 A = make_int2(0, 0);
    uint4 q0, q1, q2, q3;
    if (c < gn) {                       // pipeline prologue
        A = gl[c];
        const uint4* pp = (const uint4*)(pw + __builtin_amdgcn_readfirstlane(A.x));
        q0 = pp[0]; q1 = pp[1]; q2 = pp[2]; q3 = pp[3];
    }
    for (int i = c; i < gn; i += CH) {
        int s0  = __builtin_amdgcn_readfirstlane(A.x);
        int len = __builtin_amdgcn_readfirstlane(A.y);
        // prefetch next group's descriptor + first pw quad-batch
        int2 An = make_int2(0, 0);
        uint4 n0 = q0, n1 = q1, n2 = q2, n3 = q3;
        if (i + CH < gn) {
            An = gl[i + CH];
            const uint4* ppn = (const uint4*)(pw + __builtin_amdgcn_readfirstlane(An.x));
            n0 = ppn[0]; n1 = ppn[1]; n2 = ppn[2]; n3 = ppn[3];
        }
        float sa = 0.f;
        __half2 hgx[4];
        #pragma unroll
        for (int k = 0; k < 4; ++k) hgx[k] = __float2half2_rn(0.f);
        for (int e = 0; e < len; e += 16) {
            uint4 q[4];
            if (e == 0) {
                q[0] = q0; q[1] = q1; q[2] = q2; q[3] = q3;
            } else {
                const uint4* pp = (const uint4*)(pw + s0 + e);
                q[0] = pp[0]; q[1] = pp[1]; q[2] = pp[2]; q[3] = pp[3];
            }
            int rem = len - e;
            int p0 = (int)(q[0].x & 0xffffu);
            __half2 hw2[4]; int pv[4];
            #pragma unroll
            for (int j = 0; j < 4; ++j) {
                unsigned uv = sel4(q[j], slot);
                int ii = 4 * j + slot;
                bool valid = ii < rem;
                unsigned short hb = valid ? (unsigned short)(uv >> 16)
                                          : (unsigned short)0;
                __half hw = __ushort_as_half(hb);
                hw2[j] = __half2half2(hw);
                sa += __half2float(hw);
                pv[j] = valid ? (int)(uv & 0xffffu) : p0;
            }
            uint4 rr[4];
            #pragma unroll
            for (int j = 0; j < 4; ++j)
                if (4 * j < rem) rr[j] = *(const uint4*)(base + (size_t)pv[j] * H);
            #pragma unroll
            for (int j = 0; j < 4; ++j)
                if (4 * j < rem) {
                    const __half2* rh = (const __half2*)&rr[j];
                    hgx[0] = __hfma2(hw2[j], rh[0], hgx[0]);
                    hgx[1] = __hfma2(hw2[j], rh[1], hgx[1]);
                    hgx[2] = __hfma2(hw2[j], rh[2], hgx[2]);
                    hgx[3] = __hfma2(hw2[j], rh[3], hgx[3]);
                }
        }
        float st = sa;                        // entries split across slots
        st += __shfl_xor(st, 16, 64);
        st += __shfl_xor(st, 32, 64);
        float inv = 1.0f / st;
        ax[0] += __low2float(hgx[0])  * inv;
        ax[1] += __high2float(hgx[0]) * inv;
        ax[2] += __low2float(hgx[1])  * inv;
        ax[3] += __high2float(hgx[1]) * inv;
        ax[4] += __low2float(hgx[2])  * inv;
        ax[5] += __high2float(hgx[2]) * inv;
        ax[6] += __low2float(hgx[3])  * inv;
        ax[7] += __high2float(hgx[3]) * inv;
        A = An;
        q0 = n0; q1 = n1; q2 = n2; q3 = n3;
    }
    // reduce across slots; every lane ends with the full sum for its dims
    #pragma unroll
    for (int k = 0; k < 8; ++k) {
        ax[k] += __shfl_xor(ax[k], 16, 64);
        ax[k] += __shfl_xor(ax[k], 32, 64);
    }
    // per-wave LDS transpose (same-wave ds ordering, no barrier needed)
    if (slot == 0) {
        *(float4*)&xbuf[w][8 * sub]     = make_float4(ax[0], ax[1], ax[2], ax[3]);
        *(float4*)&xbuf[w][8 * sub + 4] = make_float4(ax[4], ax[5], ax[6], ax[7]);
    }
    float2 f2 = *(const float2*)&xbuf[w][2 * lane];
    float* dst = dsum + (size_t)d * H + 2 * lane;
    atomicAdd(dst,     f2.x);
    atomicAdd(dst + 1, f2.y);
}

// K4: one block (128 threads) per 8 drugs. w_out cached ONCE per block in
// LDS as fp16 (stride 132 halfs: 8B-aligned rows, 4-way-max bank spread)
// -> L2 w_out traffic drops 268MB -> ~34MB. Per drug: fingerprint staged
// in LDS, thread j dots LDS row j + bias + ReLU.
__global__ void k4_out(const float* __restrict__ dsum,
                       const int* __restrict__ gcnt,
                       const float* __restrict__ w_out,
                       const float* __restrict__ b_out,
                       float* __restrict__ out) {
    __shared__ __half wl[H][H + 4];
    __shared__ float fp[H];
    int b = blockIdx.x;
    int j = threadIdx.x;
    // load w_out row j -> LDS fp16 (coalesced float4 reads)
    const float4* src = (const float4*)(w_out + (size_t)j * H);
    #pragma unroll
    for (int i = 0; i < H / 4; ++i) {
        float4 v = src[i];
        wl[j][4 * i + 0] = __float2half(v.x);
        wl[j][4 * i + 1] = __float2half(v.y);
        wl[j][4 * i + 2] = __float2half(v.z);
        wl[j][4 * i + 3] = __float2half(v.w);
    }
    float bj = b_out[j];
    __syncthreads();
    for (int k = 0; k < DPB; ++k) {
        int d = b * DPB + k;
        int c = gcnt[d];
        float f = 0.f;
        if (c > 0) f = dsum[(size_t)d * H + j] / (float)c;
        fp[j] = f;
        __syncthreads();
        const float4* fvec = (const float4*)fp;
        float acc = 0.f;
        #pragma unroll
        for (int i = 0; i < H / 4; ++i) {
            float4 f4 = fvec[i];                 // broadcast read
            acc += f4.x * __half2float(wl[j][4 * i + 0]);
            acc += f4.y * __half2float(wl[j][4 * i + 1]);
            acc += f4.z * __half2float(wl[j][4 * i + 2]);
            acc += f4.w * __half2float(wl[j][4 * i + 3]);
        }
        out[(size_t)d * H + j] = fmaxf(acc + bj, 0.f);
        __syncthreads();                         // fp reused next drug
    }
}

extern "C" void kernel_launch(void* const* d_in, const int* in_sizes, int n_in,
                              void* d_out, int out_size, void* d_ws, size_t ws_size,
                              hipStream_t stream) {
    const float* protein_h = (const float*)d_in[0];
    const float* w_attn    = (const float*)d_in[1];
    const float* w_out     = (const float*)d_in[2];
    const float* b_out     = (const float*)d_in[3];
    const int*   prot_idx  = (const int*)d_in[4];
    const int*   group_ids = (const int*)d_in[5];
    const int*   g2d       = (const int*)d_in[6];

    const int E  = in_sizes[4];
    const int G  = in_sizes[6];
    const int NP = in_sizes[0] / H;

    // Workspace (~28.6 MB):
    // phh | psexp | pw(+16) | gs | ge | gl2 | [ZERO: gcnt dsum]
    __half*   phh   = (__half*)d_ws;                      // NP*H fp16
    float*    psexp = (float*)(phh + (size_t)NP * H);     // NP
    unsigned* pw    = (unsigned*)(psexp + NP);            // E + 16
    int*      gs    = (int*)(pw + E + 16);                // G (validated, not zeroed)
    int*      ge    = gs + G;                             // G
    int2*     gl2   = (int2*)(ge + G);                    // ND*MAXG
    int*      gcnt  = (int*)(gl2 + (size_t)ND * MAXG);    // ND   (zeroed in k1)
    float*    dsum  = (float*)(gcnt + ND);                // ND*H (zeroed in k1)

    // Node 1: zero + per-protein exp(logit) + fp16 table + boundary marks.
    k1<<<4096, 256, 0, stream>>>(protein_h, w_attn, group_ids, psexp, phh,
                                 gcnt, gs, ge, NP, E);

    // Node 2: pw stream + validated group-list build.
    k_p2<<<(E + 255) / 256, 256, 0, stream>>>(group_ids, prot_idx, psexp,
                                              gs, ge, g2d, gcnt, gl2, pw, E, G);

    // Node 3: drug-major fused pooling (fp16 packed math + pw pipeline).
    k_fused_drug<<<(ND * CH) / 4, 256, 0, stream>>>(phh, pw, gl2, gcnt, dsum);

    // Node 4: fingerprint + out_proj + ReLU (w_out LDS-cached, 8 drugs/block).
    k4_out<<<ND / DPB, H, 0, stream>>>(dsum, gcnt, w_out, b_out, (float*)d_out);
}